// Round 8
// baseline (40.759 us; speedup 1.0000x reference)
//
#include <hip/hip_runtime.h>
#include <math.h>

#define NC 15

typedef float f4_t __attribute__((ext_vector_type(4)));
typedef f4_t __attribute__((aligned(4))) u4_t;   // dword-aligned vec4 load (legal on CDNA)
typedef float f2_t __attribute__((ext_vector_type(2)));
typedef f2_t __attribute__((aligned(4))) u2_t;

struct Params {
    const float* p1[3];
    const float* p1d[3];
    const float* p2[3];
    const float* p2d[3];
    const float* lb[3];
    double* sums;   // [48 groups][10 terms]
};

__device__ __forceinline__ float rcp_f(float x) { return __builtin_amdgcn_rcpf(x); }

__device__ __forceinline__ float focal_f(float x, float t) {
    float e = __expf(-fabsf(x));
    float rc = rcp_f(1.0f + e);
    float sp = __logf(1.0f + e);
    float bce = fmaxf(x, 0.0f) - x * t + sp;
    float sig = (x >= 0.0f ? 1.0f : e) * rc;
    float d = t - sig;
    return bce * d * d;
}
__device__ __forceinline__ float sl1_f(float x, float t) {
    float n = fabsf(x - t);
    return n < 1.0f ? 0.5f * n * n : n - 0.5f;
}

__device__ __forceinline__ float giou_f(f4_t b, float lx, float ly, float lw, float lh) {
    float b1x0 = b.x - b.z * 0.5f, b1y0 = b.y - b.w * 0.5f;
    float b1x1 = b.x + b.z * 0.5f, b1y1 = b.y + b.w * 0.5f;
    float b2x0 = lx - lw * 0.5f, b2y0 = ly - lh * 0.5f;
    float b2x1 = lx + lw * 0.5f, b2y1 = ly + lh * 0.5f;
    float ax0 = fminf(b1x0, b1x1), ay0 = fminf(b1y0, b1y1);
    float ax1 = fmaxf(b1x0, b1x1), ay1 = fmaxf(b1y0, b1y1);
    float cx0 = fminf(b2x0, b2x1), cy0 = fminf(b2y0, b2y1);
    float cx1 = fmaxf(b2x0, b2x1), cy1 = fmaxf(b2y0, b2y1);
    float a1 = (ax1 - ax0) * (ay1 - ay0);
    float a2 = (cx1 - cx0) * (cy1 - cy0);
    float ltx = fmaxf(ax0, cx0), lty = fmaxf(ay0, cy0);
    float rbx = fminf(ax1, cx1), rby = fminf(ay1, cy1);
    float iw = fmaxf(rbx - ltx, 0.0f), ih = fmaxf(rby - lty, 0.0f);
    float inter = iw * ih;
    float uni = a1 + a2 - inter;
    float iou = inter * rcp_f(uni + 1e-6f);
    float ex0 = fminf(ax0, cx0), ey0 = fminf(ay0, cy0);
    float ex1 = fmaxf(ax1, cx1), ey1 = fmaxf(ay1, cy1);
    float ew = fmaxf(ex1 - ex0, 0.0f), eh = fmaxf(ey1 - ey0, 0.0f);
    float enc = ew * eh;
    return iou - (enc - uni) * rcp_f(enc + 1e-6f);
}

__global__ __launch_bounds__(256) void loss_head(Params P) {
    __shared__ float red[4][10];

    int tid = threadIdx.x;
    int bid = blockIdx.x;
    int head = bid & 1;
    int sub = bid >> 1;          // 0..1343
    int lvl, lblk, shift;
    float invStride;
    if (sub >= 1280)      { lvl = 2; lblk = sub - 1280; shift = 10; invStride = 1.0f / 32.0f; }
    else if (sub >= 1024) { lvl = 1; lblk = sub - 1024; shift = 12; invStride = 1.0f / 16.0f; }
    else                  { lvl = 0; lblk = sub;        shift = 14; invStride = 1.0f / 8.0f;  }
    int c = (lblk << 8) + tid;
    int batch = c >> shift;      // uniform across block

    float v0 = 0.0f, v1 = 0.0f, v2 = 0.0f, v3 = 0.0f, v4 = 0.0f,
          v5 = 0.0f, v6 = 0.0f, v7 = 0.0f, v8 = 0.0f, v9 = 0.0f;

    const float* lb = P.lb[lvl] + (size_t)c * 31;

    if (head == 0) {
        // ---------------- head 1 block ----------------
        u4_t L0 = *(const u4_t*)(lb + 0);
        u4_t L1 = *(const u4_t*)(lb + 4);
        u4_t L2 = *(const u4_t*)(lb + 8);
        u4_t L3 = *(const u4_t*)(lb + 12);
        u4_t L4 = *(const u4_t*)(lb + 16);
        u4_t L5 = *(const u4_t*)(lb + 20);
        u4_t L6 = *(const u4_t*)(lb + 24);
        u2_t L7 = *(const u2_t*)(lb + 28);
        float c14 = lb[30];
        const float* pa = P.p1d[lvl] + (size_t)c * 13;
        u4_t A0 = *(const u4_t*)(pa + 0);
        u4_t A1 = *(const u4_t*)(pa + 4);
        u4_t A2 = *(const u4_t*)(pa + 8);
        float A3 = pa[12];
        float conf1 = P.p1[lvl][(size_t)c * 10 + 9];
        __builtin_amdgcn_sched_barrier(0);   // all loads issued before compute

        float lx = L0.x, ly = L0.y, lw = L0.z, lh = L0.w;
        float lr = L3.x, flag = L3.y, mix = L3.z, area = L3.w;
        float gh = fmaxf(fmaxf(fmaxf(L4.x, L4.y), fmaxf(L4.z, L4.w)),
                   fmaxf(fmaxf(fmaxf(L5.x, L5.y), fmaxf(L5.z, L5.w)),
                   fmaxf(fmaxf(fmaxf(L6.x, L6.y), fmaxf(L6.z, L6.w)),
                         fmaxf(fmaxf(L7.x, L7.y), c14))));
        float obj   = (flag == 1.0f) ? 1.0f : 0.0f;
        float noobj = (flag == 0.0f) ? 1.0f : 0.0f;
        float fuzzy = 1.0f - obj - noobj;
        float conf_t = obj * 0.99f + 0.005f;
        float aw = area + ((area == 0.0f) ? 1.0f : 0.0f);
        float bls = 2.0f - lw * lh * (1.0f / (1024.0f * 1024.0f));

        float xiou = giou_f(A0, lx, ly, lw, lh);
        float siou = bls * (1.0f - fminf(fmaxf(xiou, 0.0f), 1.0f));
        float d0 = A1.x - L2.x, d1 = A1.y - L2.y, d2 = A1.z - L2.z, d3 = A1.w - L2.w;
        float sobb = d0 * d0 + d1 * d1 + d2 * d2 + d3 * d3;
        float dr = A2.x - lr;
        float sarea = dr * dr;
        float off = __expf(-(siou + sobb + sarea));
        float g = (gh + off) * 0.5f;
        float bg = noobj + fuzzy * ((g < 0.3f) ? 1.0f : 0.0f) * (1.0f - fuzzy * g);
        float fg = obj * ((g >= 0.3f) ? 1.0f : 0.0f);
        float foc = focal_f(conf1, conf_t);
        float fma_ = fg * mix * aw;
        v0 = fg * foc * mix * g;
        v1 = bg * foc * mix;
        v2 = fma_ * siou;
        v3 = fma_ * sobb;
        v4 = fma_ * sarea;
        float sl = sl1_f(A2.y * invStride, L1.x * invStride)
                 + sl1_f(A2.z * invStride, L1.y * invStride)
                 + sl1_f(A2.w * invStride, L1.z * invStride)
                 + sl1_f(A3 * invStride,   L1.w * invStride);
        v5 = fg * bls * sl * mix * aw;
        v9 = obj;   // counted once per cell (head-1 blocks only)
    } else {
        // ---------------- head 2 block ----------------
        u4_t L0 = *(const u4_t*)(lb + 0);
        u4_t L1 = *(const u4_t*)(lb + 4);
        u4_t L2 = *(const u4_t*)(lb + 8);
        u4_t L3 = *(const u4_t*)(lb + 12);
        u4_t L4 = *(const u4_t*)(lb + 16);
        u4_t L5 = *(const u4_t*)(lb + 20);
        u4_t L6 = *(const u4_t*)(lb + 24);
        u2_t L7 = *(const u2_t*)(lb + 28);
        float c14 = lb[30];
        const float* pb = P.p2d[lvl] + (size_t)c * 13;
        u4_t B0 = *(const u4_t*)(pb + 0);
        u4_t B1 = *(const u4_t*)(pb + 4);
        u4_t B2 = *(const u4_t*)(pb + 8);
        float B3 = pb[12];
        const float* pq = P.p2[lvl] + (size_t)c * 25 + 9;   // conf + 15 cls
        u4_t Q0 = *(const u4_t*)(pq + 0);
        u4_t Q1 = *(const u4_t*)(pq + 4);
        u4_t Q2 = *(const u4_t*)(pq + 8);
        u4_t Q3 = *(const u4_t*)(pq + 12);
        __builtin_amdgcn_sched_barrier(0);   // all loads issued before compute

        float lx = L0.x, ly = L0.y, lw = L0.z, lh = L0.w;
        float lr = L3.x, flag = L3.y, mix = L3.z, area = L3.w;
        float cl[NC] = {L4.x, L4.y, L4.z, L4.w, L5.x, L5.y, L5.z, L5.w,
                        L6.x, L6.y, L6.z, L6.w, L7.x, L7.y, c14};
        float gh = 0.0f;
        unsigned nzm = 0u;
#pragma unroll
        for (int k = 0; k < NC; ++k) {
            gh = fmaxf(gh, cl[k]);
            if (cl[k] != 0.0f) nzm |= (1u << k);
        }
        float obj   = (flag == 1.0f) ? 1.0f : 0.0f;
        float noobj = (flag == 0.0f) ? 1.0f : 0.0f;
        float fuzzy = 1.0f - obj - noobj;
        float conf_t = obj * 0.99f + 0.005f;
        float aw = area + ((area == 0.0f) ? 1.0f : 0.0f);
        float bls = 2.0f - lw * lh * (1.0f / (1024.0f * 1024.0f));

        float xiou = giou_f(B0, lx, ly, lw, lh);
        float siou2 = bls * (1.0f - fminf(fmaxf(xiou, 0.0f), 1.0f));
        float d0 = B1.x - L2.x, d1 = B1.y - L2.y, d2 = B1.z - L2.z, d3 = B1.w - L2.w;
        float sobb2 = d0 * d0 + d1 * d1 + d2 * d2 + d3 * d3;
        float dr = B2.x - lr;
        float sarea2 = dr * dr;
        float off2 = __expf(-(siou2 + sobb2 + sarea2));
        float sl2 = sl1_f(B2.y * invStride, L1.x * invStride)
                  + sl1_f(B2.z * invStride, L1.y * invStride)
                  + sl1_f(B2.w * invStride, L1.z * invStride)
                  + sl1_f(B3 * invStride,   L1.w * invStride);

        float conf2 = Q0.x;
        float g = (gh + off2) * 0.5f;
        float bg = noobj + fuzzy * ((g < 0.3f) ? 1.0f : 0.0f) * (1.0f - fuzzy * g);
        float fg = obj * ((g >= 0.3f) ? 1.0f : 0.0f);
        float foc = focal_f(conf2, conf_t);
        v0 = fg * foc * mix * g;
        v1 = bg * foc * mix;

        float cx[NC] = {Q0.y, Q0.z, Q0.w, Q1.x, Q1.y, Q1.z, Q1.w,
                        Q2.x, Q2.y, Q2.z, Q2.w, Q3.x, Q3.y, Q3.z, Q3.w};
        float pos = 0.0f, neg = 0.0f, wsum = 0.0f, clsb = 0.0f;
#pragma unroll
        for (int k = 0; k < NC; ++k) {
            float x = cx[k];
            bool nz = (nzm >> k) & 1u;
            float smn = (nz ? 0.99f : 0.0f) + (0.01f / 15.0f);
            float e = __expf(-fabsf(x));
            float sp = __logf(1.0f + e);
            float mx = fmaxf(x, 0.0f);
            float b0 = mx - x * smn + sp;
            clsb += b0;
            if (nz) {
                pos += mx - x * (smn * off2) + sp;
                wsum += (x >= 0.0f ? 1.0f : e) * rcp_f(1.0f + e);
            } else {
                neg += b0;
            }
        }
        float wgq = (wsum + gh) * 0.5f;
        float oma = obj * mix * aw;
        v6 = oma * pos;
        v7 = oma * neg;
        float fmaw = fg * mix * aw * wgq;
        v2 = fmaw * siou2;
        v3 = fmaw * sobb2;
        v4 = fmaw * sarea2;
        v5 = fg * bls * sl2 * mix * aw * wgq;
        v8 = fg * clsb * mix * aw;
    }

    // ---------------- reduction: wave shuffle -> LDS -> 10 f64 atomics ----------------
#pragma unroll
    for (int o = 32; o > 0; o >>= 1) {
        v0 += __shfl_down(v0, o);
        v1 += __shfl_down(v1, o);
        v2 += __shfl_down(v2, o);
        v3 += __shfl_down(v3, o);
        v4 += __shfl_down(v4, o);
        v5 += __shfl_down(v5, o);
        v6 += __shfl_down(v6, o);
        v7 += __shfl_down(v7, o);
        v8 += __shfl_down(v8, o);
        v9 += __shfl_down(v9, o);
    }
    int lane = tid & 63, wid = tid >> 6;
    if (lane == 0) {
        red[wid][0] = v0; red[wid][1] = v1; red[wid][2] = v2; red[wid][3] = v3;
        red[wid][4] = v4; red[wid][5] = v5; red[wid][6] = v6; red[wid][7] = v7;
        red[wid][8] = v8; red[wid][9] = v9;
    }
    __syncthreads();
    if (tid < 10) {
        float total = red[0][tid] + red[1][tid] + red[2][tid] + red[3][tid];
        if (total != 0.0f)
            atomicAdd(&P.sums[((size_t)((lvl << 4) + batch)) * 10 + tid], (double)total);
    }
}

__global__ __launch_bounds__(64) void finalize_kernel(const double* __restrict__ S,
                                                      float* __restrict__ out) {
    int lane = threadIdx.x;
    double loc[10];
#pragma unroll
    for (int t = 0; t < 10; ++t) loc[t] = 0.0;
    if (lane < 48) {
        const double* s = S + (size_t)lane * 10;
        double invN = 1.0 / fmax(s[9], 1.0);
#pragma unroll
        for (int t = 0; t < 9; ++t) loc[t] = s[t] * invN;
    }
#pragma unroll
    for (int t = 0; t < 9; ++t) {
#pragma unroll
        for (int o = 32; o > 0; o >>= 1) loc[t] += __shfl_down(loc[t], o);
    }
    if (lane == 0) {
        const double invB = 1.0 / 16.0;
        double fg  = loc[0] * invB;
        double bg  = loc[1] * invB;
        double iou = loc[2] * invB * 0.5;
        double s_  = loc[3] * invB * 0.5;
        double r   = loc[4] * invB * 8.0;    // 16 * avg-of-2
        double l   = loc[5] * invB * 0.1;    // 0.2 * avg-of-2
        double pos = loc[6] * invB * 28.0;   // *(NC-1)=14, then *2
        double neg = loc[7] * invB * 2.0;
        double cls = loc[8] * invB;
        double loss = fg + bg + iou + s_ + r + pos + neg + l;
        out[0] = (float)loss; out[1] = (float)fg; out[2] = (float)bg;
        out[3] = (float)pos;  out[4] = (float)neg; out[5] = (float)iou;
        out[6] = (float)cls;  out[7] = (float)s_;  out[8] = (float)r;
        out[9] = (float)l;
    }
}

extern "C" void kernel_launch(void* const* d_in, const int* in_sizes, int n_in,
                              void* d_out, int out_size, void* d_ws, size_t ws_size,
                              hipStream_t stream) {
    (void)in_sizes; (void)n_in; (void)out_size; (void)ws_size;
    double* sums = (double*)d_ws;   // 48 groups * 10 terms
    hipMemsetAsync(d_ws, 0, 48 * 10 * sizeof(double), stream);

    Params P;
    for (int lvl = 0; lvl < 3; ++lvl) {
        P.p1[lvl]  = (const float*)d_in[lvl * 5 + 0];
        P.p1d[lvl] = (const float*)d_in[lvl * 5 + 1];
        P.p2[lvl]  = (const float*)d_in[lvl * 5 + 2];
        P.p2d[lvl] = (const float*)d_in[lvl * 5 + 3];
        P.lb[lvl]  = (const float*)d_in[lvl * 5 + 4];
    }
    P.sums = sums;

    loss_head<<<dim3(2688), dim3(256), 0, stream>>>(P);
    finalize_kernel<<<dim3(1), dim3(64), 0, stream>>>(sums, (float*)d_out);
}

// Round 9
// 33.981 us; speedup vs baseline: 1.1995x; 1.1995x over previous
//
#include <hip/hip_runtime.h>
#include <math.h>

#define NC 15

typedef float f4_t __attribute__((ext_vector_type(4)));
typedef f4_t __attribute__((aligned(4))) u4_t;   // dword-aligned vec4 load (legal on CDNA)

struct Params {
    const float* p1[3];
    const float* p1d[3];
    const float* p2[3];
    const float* p2d[3];
    const float* lb[3];
    double* sums;   // [48 groups][10 terms]
};

__device__ __forceinline__ float rcp_f(float x) { return __builtin_amdgcn_rcpf(x); }

__device__ __forceinline__ float focal_f(float x, float t) {
    float e = __expf(-fabsf(x));
    float rc = rcp_f(1.0f + e);
    float sp = __logf(1.0f + e);
    float bce = fmaxf(x, 0.0f) - x * t + sp;
    float sig = (x >= 0.0f ? 1.0f : e) * rc;
    float d = t - sig;
    return bce * d * d;
}
__device__ __forceinline__ float sl1_f(float x, float t) {
    float n = fabsf(x - t);
    return n < 1.0f ? 0.5f * n * n : n - 0.5f;
}

__device__ __forceinline__ float giou_f(f4_t b, float lx, float ly, float lw, float lh) {
    float b1x0 = b.x - b.z * 0.5f, b1y0 = b.y - b.w * 0.5f;
    float b1x1 = b.x + b.z * 0.5f, b1y1 = b.y + b.w * 0.5f;
    float b2x0 = lx - lw * 0.5f, b2y0 = ly - lh * 0.5f;
    float b2x1 = lx + lw * 0.5f, b2y1 = ly + lh * 0.5f;
    float ax0 = fminf(b1x0, b1x1), ay0 = fminf(b1y0, b1y1);
    float ax1 = fmaxf(b1x0, b1x1), ay1 = fmaxf(b1y0, b1y1);
    float cx0 = fminf(b2x0, b2x1), cy0 = fminf(b2y0, b2y1);
    float cx1 = fmaxf(b2x0, b2x1), cy1 = fmaxf(b2y0, b2y1);
    float a1 = (ax1 - ax0) * (ay1 - ay0);
    float a2 = (cx1 - cx0) * (cy1 - cy0);
    float ltx = fmaxf(ax0, cx0), lty = fmaxf(ay0, cy0);
    float rbx = fminf(ax1, cx1), rby = fminf(ay1, cy1);
    float iw = fmaxf(rbx - ltx, 0.0f), ih = fmaxf(rby - lty, 0.0f);
    float inter = iw * ih;
    float uni = a1 + a2 - inter;
    float iou = inter * rcp_f(uni + 1e-6f);
    float ex0 = fminf(ax0, cx0), ey0 = fminf(ay0, cy0);
    float ex1 = fmaxf(ax1, cx1), ey1 = fmaxf(ay1, cy1);
    float ew = fmaxf(ex1 - ex0, 0.0f), eh = fmaxf(ey1 - ey0, 0.0f);
    float enc = ew * eh;
    return iou - (enc - uni) * rcp_f(enc + 1e-6f);
}

__global__ __launch_bounds__(256, 5) void loss_all(Params P) {
    __shared__ __align__(16) float sL[7936];   // label: 256 cells * 31 floats
    __shared__ float red[4][10];

    int tid = threadIdx.x;
    int bid = blockIdx.x;
    int lvl, lblk, shift;
    float invStride;
    if (bid >= 1280)      { lvl = 2; lblk = bid - 1280; shift = 10; invStride = 1.0f / 32.0f; }
    else if (bid >= 1024) { lvl = 1; lblk = bid - 1024; shift = 12; invStride = 1.0f / 16.0f; }
    else                  { lvl = 0; lblk = bid;        shift = 14; invStride = 1.0f / 8.0f;  }
    int cell0 = lblk << 8;
    int c = cell0 + tid;
    int batch = c >> shift;   // uniform across block

    // ---- stage label coalesced through LDS (the fat, transaction-heavy array) ----
    {
        const float4* gLv = (const float4*)(P.lb[lvl] + (size_t)cell0 * 31);  // 1984 v4, 16B-aligned
        float4* vL = (float4*)sL;
#pragma unroll
        for (int k = 0; k < 7; ++k) vL[tid + 256 * k] = gLv[tid + 256 * k];
        if (tid < 192) vL[1792 + tid] = gLv[1792 + tid];
    }

    // ---- direct register loads for the dense-use slices ----
    const float* pa = P.p1d[lvl] + (size_t)c * 13;
    u4_t A0 = *(const u4_t*)(pa + 0);
    u4_t A1 = *(const u4_t*)(pa + 4);
    u4_t A2 = *(const u4_t*)(pa + 8);
    float A3 = pa[12];
    const float* pb = P.p2d[lvl] + (size_t)c * 13;
    u4_t B0 = *(const u4_t*)(pb + 0);
    u4_t B1 = *(const u4_t*)(pb + 4);
    u4_t B2 = *(const u4_t*)(pb + 8);
    float B3 = pb[12];
    const float* pq = P.p2[lvl] + (size_t)c * 25 + 9;   // conf + 15 cls
    u4_t Q0 = *(const u4_t*)(pq + 0);
    u4_t Q1 = *(const u4_t*)(pq + 4);
    u4_t Q2 = *(const u4_t*)(pq + 8);
    u4_t Q3 = *(const u4_t*)(pq + 12);
    float conf1 = P.p1[lvl][(size_t)c * 10 + 9];

    __syncthreads();

    // ---- label extraction from LDS (stride 31: conflict-free, 2 lanes/bank) ----
    const float* L = sL + tid * 31;
    float lx = L[0], ly = L[1], lw = L[2], lh = L[3];
    float l1 = L[4], l2 = L[5], l3 = L[6], l4 = L[7];
    float a0 = L[8], a1 = L[9], a2 = L[10], a3 = L[11];
    float lr = L[12];
    float flag = L[13];
    float mix = L[14];
    float area = L[15];
    float gh = 0.0f;
    unsigned nzm = 0u;
#pragma unroll
    for (int k = 0; k < NC; ++k) {
        float cv = L[16 + k];
        gh = fmaxf(gh, cv);
        if (cv != 0.0f) nzm |= (1u << k);
    }

    float obj   = (flag == 1.0f) ? 1.0f : 0.0f;
    float noobj = (flag == 0.0f) ? 1.0f : 0.0f;
    float fuzzy = 1.0f - obj - noobj;
    float conf_t = obj * 0.99f + 0.005f;
    float aw = area + ((area == 0.0f) ? 1.0f : 0.0f);
    float bls = 2.0f - lw * lh * (1.0f / (1024.0f * 1024.0f));

    float v0, v1, v2, v3, v4, v5, v6, v7, v8, v9;

    // ---------------- head 1 ----------------
    {
        float xiou = giou_f(A0, lx, ly, lw, lh);
        float siou = bls * (1.0f - fminf(fmaxf(xiou, 0.0f), 1.0f));
        float d0 = A1.x - a0, d1 = A1.y - a1, d2 = A1.z - a2, d3 = A1.w - a3;
        float sobb = d0 * d0 + d1 * d1 + d2 * d2 + d3 * d3;
        float dr = A2.x - lr;
        float sarea = dr * dr;
        float off = __expf(-(siou + sobb + sarea));
        float g = (gh + off) * 0.5f;
        float bg = noobj + fuzzy * ((g < 0.3f) ? 1.0f : 0.0f) * (1.0f - fuzzy * g);
        float fg = obj * ((g >= 0.3f) ? 1.0f : 0.0f);
        float foc = focal_f(conf1, conf_t);
        float fma_ = fg * mix * aw;
        v0 = fg * foc * mix * g;
        v1 = bg * foc * mix;
        v2 = fma_ * siou;
        v3 = fma_ * sobb;
        v4 = fma_ * sarea;
        float sl = sl1_f(A2.y * invStride, l1 * invStride)
                 + sl1_f(A2.z * invStride, l2 * invStride)
                 + sl1_f(A2.w * invStride, l3 * invStride)
                 + sl1_f(A3 * invStride,   l4 * invStride);
        v5 = fg * bls * sl * mix * aw;
    }

    // ---------------- head 2 ----------------
    {
        float xiou = giou_f(B0, lx, ly, lw, lh);
        float siou2 = bls * (1.0f - fminf(fmaxf(xiou, 0.0f), 1.0f));
        float d0 = B1.x - a0, d1 = B1.y - a1, d2 = B1.z - a2, d3 = B1.w - a3;
        float sobb2 = d0 * d0 + d1 * d1 + d2 * d2 + d3 * d3;
        float dr = B2.x - lr;
        float sarea2 = dr * dr;
        float off2 = __expf(-(siou2 + sobb2 + sarea2));
        float sl2 = sl1_f(B2.y * invStride, l1 * invStride)
                  + sl1_f(B2.z * invStride, l2 * invStride)
                  + sl1_f(B2.w * invStride, l3 * invStride)
                  + sl1_f(B3 * invStride,   l4 * invStride);

        float conf2 = Q0.x;
        float g = (gh + off2) * 0.5f;
        float bg = noobj + fuzzy * ((g < 0.3f) ? 1.0f : 0.0f) * (1.0f - fuzzy * g);
        float fg = obj * ((g >= 0.3f) ? 1.0f : 0.0f);
        float foc = focal_f(conf2, conf_t);
        v0 += fg * foc * mix * g;
        v1 += bg * foc * mix;

        float cx[NC] = {Q0.y, Q0.z, Q0.w, Q1.x, Q1.y, Q1.z, Q1.w,
                        Q2.x, Q2.y, Q2.z, Q2.w, Q3.x, Q3.y, Q3.z, Q3.w};
        float pos = 0.0f, neg = 0.0f, wsum = 0.0f, clsb = 0.0f;
#pragma unroll
        for (int k = 0; k < NC; ++k) {
            float x = cx[k];
            bool nz = (nzm >> k) & 1u;
            float smn = (nz ? 0.99f : 0.0f) + (0.01f / 15.0f);
            float e = __expf(-fabsf(x));
            float sp = __logf(1.0f + e);
            float mx = fmaxf(x, 0.0f);
            float b0 = mx - x * smn + sp;
            clsb += b0;
            if (nz) {
                pos += mx - x * (smn * off2) + sp;
                wsum += (x >= 0.0f ? 1.0f : e) * rcp_f(1.0f + e);
            } else {
                neg += b0;
            }
        }
        float wgq = (wsum + gh) * 0.5f;
        float oma = obj * mix * aw;
        v6 = oma * pos;
        v7 = oma * neg;
        float fmaw = fg * mix * aw * wgq;
        v2 += fmaw * siou2;
        v3 += fmaw * sobb2;
        v4 += fmaw * sarea2;
        v5 += fg * bls * sl2 * mix * aw * wgq;
        v8 = fg * clsb * mix * aw;
    }
    v9 = obj;

    // ---------------- reduction: wave shuffle -> LDS -> 10 f64 atomics ----------------
#pragma unroll
    for (int o = 32; o > 0; o >>= 1) {
        v0 += __shfl_down(v0, o);
        v1 += __shfl_down(v1, o);
        v2 += __shfl_down(v2, o);
        v3 += __shfl_down(v3, o);
        v4 += __shfl_down(v4, o);
        v5 += __shfl_down(v5, o);
        v6 += __shfl_down(v6, o);
        v7 += __shfl_down(v7, o);
        v8 += __shfl_down(v8, o);
        v9 += __shfl_down(v9, o);
    }
    int lane = tid & 63, wid = tid >> 6;
    if (lane == 0) {
        red[wid][0] = v0; red[wid][1] = v1; red[wid][2] = v2; red[wid][3] = v3;
        red[wid][4] = v4; red[wid][5] = v5; red[wid][6] = v6; red[wid][7] = v7;
        red[wid][8] = v8; red[wid][9] = v9;
    }
    __syncthreads();
    if (tid < 10) {
        float total = red[0][tid] + red[1][tid] + red[2][tid] + red[3][tid];
        atomicAdd(&P.sums[((size_t)((lvl << 4) + batch)) * 10 + tid], (double)total);
    }
}

__global__ __launch_bounds__(64) void finalize_kernel(const double* __restrict__ S,
                                                      float* __restrict__ out) {
    int lane = threadIdx.x;
    double loc[10];
#pragma unroll
    for (int t = 0; t < 10; ++t) loc[t] = 0.0;
    if (lane < 48) {
        const double* s = S + (size_t)lane * 10;
        double invN = 1.0 / fmax(s[9], 1.0);
#pragma unroll
        for (int t = 0; t < 9; ++t) loc[t] = s[t] * invN;
    }
#pragma unroll
    for (int t = 0; t < 9; ++t) {
#pragma unroll
        for (int o = 32; o > 0; o >>= 1) loc[t] += __shfl_down(loc[t], o);
    }
    if (lane == 0) {
        const double invB = 1.0 / 16.0;
        double fg  = loc[0] * invB;
        double bg  = loc[1] * invB;
        double iou = loc[2] * invB * 0.5;
        double s_  = loc[3] * invB * 0.5;
        double r   = loc[4] * invB * 8.0;    // 16 * avg-of-2
        double l   = loc[5] * invB * 0.1;    // 0.2 * avg-of-2
        double pos = loc[6] * invB * 28.0;   // *(NC-1)=14, then *2
        double neg = loc[7] * invB * 2.0;
        double cls = loc[8] * invB;
        double loss = fg + bg + iou + s_ + r + pos + neg + l;
        out[0] = (float)loss; out[1] = (float)fg; out[2] = (float)bg;
        out[3] = (float)pos;  out[4] = (float)neg; out[5] = (float)iou;
        out[6] = (float)cls;  out[7] = (float)s_;  out[8] = (float)r;
        out[9] = (float)l;
    }
}

extern "C" void kernel_launch(void* const* d_in, const int* in_sizes, int n_in,
                              void* d_out, int out_size, void* d_ws, size_t ws_size,
                              hipStream_t stream) {
    (void)in_sizes; (void)n_in; (void)out_size; (void)ws_size;
    double* sums = (double*)d_ws;   // 48 groups * 10 terms
    hipMemsetAsync(d_ws, 0, 48 * 10 * sizeof(double), stream);

    Params P;
    for (int lvl = 0; lvl < 3; ++lvl) {
        P.p1[lvl]  = (const float*)d_in[lvl * 5 + 0];
        P.p1d[lvl] = (const float*)d_in[lvl * 5 + 1];
        P.p2[lvl]  = (const float*)d_in[lvl * 5 + 2];
        P.p2d[lvl] = (const float*)d_in[lvl * 5 + 3];
        P.lb[lvl]  = (const float*)d_in[lvl * 5 + 4];
    }
    P.sums = sums;

    loss_all<<<dim3(1344), dim3(256), 0, stream>>>(P);
    finalize_kernel<<<dim3(1), dim3(64), 0, stream>>>(sums, (float*)d_out);
}